// Round 14
// baseline (542.742 us; speedup 1.0000x reference)
//
#include <hip/hip_runtime.h>
#include <cstdint>
#include <cstddef>

#define D_MODEL 1024
#define D_FF 4096
#define NTOK 4096
#define LN_EPS 1e-5f

typedef __bf16 bf16x8 __attribute__((ext_vector_type(8)));
typedef float f32x4 __attribute__((ext_vector_type(4)));
typedef unsigned short u16x4 __attribute__((ext_vector_type(4)));
typedef unsigned short u16x8 __attribute__((ext_vector_type(8)));

static __device__ __forceinline__ unsigned short f2bf(float f) {
    union { float f; unsigned u; } v; v.f = f;
    unsigned r = v.u + 0x7fffu + ((v.u >> 16) & 1u);
    return (unsigned short)(r >> 16);
}

static __device__ __forceinline__ float b2f(unsigned short u) {
    union { unsigned u; float f; } v; v.u = (unsigned)u << 16;
    return v.f;
}

// tanh-form GELU as x*sigmoid(2u), log2e pre-folded (proven round 7)
static __device__ __forceinline__ float gelu_fast(float x) {
    float x2 = x * x;
    float a2 = x * __builtin_fmaf(-0.1029432f, x2, -2.3022084f);  // -2u*log2(e)
    float e = __builtin_amdgcn_exp2f(a2);
    return x * __builtin_amdgcn_rcpf(1.0f + e);
}

static __device__ __forceinline__ void gload16(const void* g, void* l) {
    __builtin_amdgcn_global_load_lds(
        (const __attribute__((address_space(1))) void*)g,
        (__attribute__((address_space(3))) void*)l, 16, 0, 0);
}

// padded (256-aligned) prefix offsets of the 4 variable experts in the row slab
static __device__ __forceinline__ void seg_of(const int* cnt, int seg[4], int pc[4]) {
    int o = 2 * NTOK;
    #pragma unroll
    for (int e = 0; e < 4; ++e) {
        int c = cnt[e * 32];
        pc[e] = (c + 255) & ~255;
        seg[e] = o;
        o += pc[e];
    }
}

// ---------------- W [E][K][N] f32 -> Wt [E][N][K] bf16 ----------------
__global__ __launch_bounds__(256) void transpose_kernel(const float* __restrict__ W,
                                                        unsigned short* __restrict__ Wt,
                                                        int K, int N) {
    __shared__ unsigned short t[64][65];
    int k0 = blockIdx.y * 64, n0 = blockIdx.x * 64;
    const float* We = W + (size_t)blockIdx.z * K * N;
    unsigned short* Wte = Wt + (size_t)blockIdx.z * K * N;
    #pragma unroll
    for (int i = 0; i < 4; ++i) {
        int idx = threadIdx.x + i * 256;
        int kr = idx >> 4, c4 = idx & 15;
        f32x4 v = *(const f32x4*)&We[(size_t)(k0 + kr) * N + n0 + c4 * 4];
        #pragma unroll
        for (int j = 0; j < 4; ++j) t[c4 * 4 + j][kr] = f2bf(v[j]);
    }
    __syncthreads();
    #pragma unroll
    for (int i = 0; i < 2; ++i) {
        int idx = threadIdx.x + i * 256;
        int nr = idx >> 3, ck = idx & 7;
        u16x8 w;
        #pragma unroll
        for (int j = 0; j < 8; ++j) w[j] = t[nr][ck * 8 + j];
        *(u16x8*)&Wte[(size_t)(n0 + nr) * K + k0 + ck * 8] = w;
    }
}

// ------- router (fused x->bf16 convert): logits + top-2 + compaction + xb -----
__global__ __launch_bounds__(256) void router_kernel(
        const float* __restrict__ x, const float* __restrict__ rW,
        float* __restrict__ logits, int* __restrict__ selpk,
        int* __restrict__ slotpk, int* __restrict__ cnt, int* __restrict__ list,
        unsigned short* __restrict__ xb) {
    __shared__ int se[8];
    __shared__ int sslot[8];
    int wid = threadIdx.x >> 6, lane = threadIdx.x & 63;
    int t = blockIdx.x * 4 + wid;
    const float* xr = x + (size_t)t * D_MODEL;
    unsigned short* xbr = xb + (size_t)t * D_MODEL;
    float a0 = 0.f, a1 = 0.f, a2 = 0.f, a3 = 0.f;
    #pragma unroll
    for (int i = 0; i < 4; ++i) {
        int d4 = lane + i * 64;                 // float4 index within row
        f32x4 xv = *(const f32x4*)&xr[d4 * 4];
        u16x4 bo;
        #pragma unroll
        for (int j = 0; j < 4; ++j) {
            float xj = xv[j];
            f32x4 wv = *(const f32x4*)&rW[(d4 * 4 + j) * 4];
            a0 = __builtin_fmaf(xj, wv[0], a0);
            a1 = __builtin_fmaf(xj, wv[1], a1);
            a2 = __builtin_fmaf(xj, wv[2], a2);
            a3 = __builtin_fmaf(xj, wv[3], a3);
            bo[j] = f2bf(xj);
        }
        *(u16x4*)&xbr[d4 * 4] = bo;
    }
    #pragma unroll
    for (int off = 32; off; off >>= 1) {
        a0 += __shfl_xor(a0, off); a1 += __shfl_xor(a1, off);
        a2 += __shfl_xor(a2, off); a3 += __shfl_xor(a3, off);
    }
    if (lane == 0) {
        float l[4] = {a0, a1, a2, a3};
        logits[t * 4 + 0] = a0; logits[t * 4 + 1] = a1;
        logits[t * 4 + 2] = a2; logits[t * 4 + 3] = a3;
        int e0 = 0; float b = l[0];
        #pragma unroll
        for (int e = 1; e < 4; ++e) if (l[e] > b) { b = l[e]; e0 = e; }
        int e1 = -1; float b2 = -1e30f;
        #pragma unroll
        for (int e = 0; e < 4; ++e) {
            if (e == e0) continue;
            if (l[e] > b2) { b2 = l[e]; e1 = e; }
        }
        se[wid * 2] = e0; se[wid * 2 + 1] = e1;
    }
    __syncthreads();
    if (threadIdx.x == 0) {
        int cnts[4] = {0, 0, 0, 0}, base[4];
        #pragma unroll
        for (int k = 0; k < 8; ++k) cnts[se[k]]++;
        #pragma unroll
        for (int e = 0; e < 4; ++e)
            if (cnts[e]) base[e] = atomicAdd(&cnt[e * 32], cnts[e]);
        int run[4] = {0, 0, 0, 0};
        #pragma unroll
        for (int k = 0; k < 8; ++k) {
            int e = se[k];
            int s = base[e] + run[e]++;
            sslot[k] = s;
            list[e * NTOK + s] = blockIdx.x * 4 + (k >> 1);
        }
    }
    __syncthreads();
    if (lane == 0) {
        selpk[t] = se[wid * 2] | (se[wid * 2 + 1] << 8);
        slotpk[t] = sslot[wid * 2] | (sslot[wid * 2 + 1] << 16);
    }
}

// -------- 8-wave 2-barrier GEMM, parameterized per-wave tile (r13 + fix) ------
// Block = 512 threads = WAVES_M x WAVES_N waves; per-wave C = (BM/WAVES_M) x
// (BN/WAVES_N). pass1: per-wave 128x64 (12 ds_reads : 32 MFMA per kk);
// pass2: 64x64 (r12-identical config).
// ROUND-13 LESSON: with no min-waves hint the compiler's heuristic chose 96
// VGPR for the 8-wave kernel and SPILLED acc[8][4] (WRITE_SIZE 250 MB scratch).
// __launch_bounds__(512, 2): min 2 waves/EU -> VGPR cap 256, no spill; pass2
// (60 VGPR) unaffected. r8's disaster was (512,6) -> cap ~85 -> hard spill.
// Simple 2-barrier loop (5 pipeline variants all lost to multi-block TLP).
// Quad-XCD swizzle: bijective for nwg%32==0; quads of 4 share an A-panel.
template<int GELU, int BM, int BN, int WAVES_M, int WAVES_N, int GX, int GY>
__global__ __launch_bounds__(512, 2) void gemm_kernel(
        const unsigned short* __restrict__ A, const unsigned short* __restrict__ B,
        const float* __restrict__ bias, int bias_stride, int ldo,
        unsigned short* __restrict__ out,
        const int* __restrict__ cnt, const int* __restrict__ list, int K) {
    constexpr int WMLD = BM / 64, WNLD = BN / 64;          // staging loads/thread
    constexpr int MR = BM / WAVES_M / 16, NR = BN / WAVES_N / 16;
    __shared__ unsigned short As[BM * 64];
    __shared__ unsigned short Bs[BN * 64];

    // balanced quad-XCD swizzle (nwg = GX*GY*6, multiple of 32 for both passes)
    const int D = blockIdx.x + GX * (blockIdx.y + GY * blockIdx.z);
    const int tq = D >> 3;
    const int W = ((D & 7) << 2) + ((tq >> 2) << 5) + (tq & 3);
    const int bx = W % GX;
    const int rem = W / GX;
    const int by = rem % GY;
    const int e  = rem / GY;

    const int tid = threadIdx.x, lane = tid & 63, w = tid >> 6;
    int ecnt = NTOK, rowbase;
    if (e < 2) {
        rowbase = e * NTOK + by * BM;
    } else {
        int seg[4], pc[4];
        seg_of(cnt, seg, pc);
        int ev = e - 2;
        ecnt = cnt[ev * 32];
        if (by * BM >= pc[ev]) return;   // before any barrier
        rowbase = seg[ev] + by * BM;
    }
    const int n0 = bx * BN;
    const unsigned short* Be = B + (size_t)e * (D_FF * D_MODEL);

    // per-thread staging sources (pre-swizzled source piece, linear LDS dest);
    // load i covers rows i*64 + w*8 + (lane>>3), piece (lane&7)^(row&7)
    const unsigned short* asrc[WMLD];
    const unsigned short* bsrc[WNLD];
    #pragma unroll
    for (int i = 0; i < WMLD; ++i) {
        int row = i * 64 + w * 8 + (lane >> 3);
        int kc = lane & 7;
        size_t arow;
        if (GELU) {
            int s = by * BM + row;
            if (e < 2) arow = (size_t)s;
            else       arow = (size_t)((s < ecnt) ? list[(e - 2) * NTOK + s] : 0);
        } else {
            arow = (size_t)(rowbase + row);
        }
        asrc[i] = A + arow * K + ((kc ^ (row & 7)) << 3);
    }
    #pragma unroll
    for (int i = 0; i < WNLD; ++i) {
        int row = i * 64 + w * 8 + (lane >> 3);
        int kc = lane & 7;
        bsrc[i] = Be + (size_t)(n0 + row) * K + ((kc ^ (row & 7)) << 3);
    }

    const int wm = (w / WAVES_N) * (BM / WAVES_M);
    const int wn = (w % WAVES_N) * (BN / WAVES_N);
    const int rl = lane & 15, kq = lane >> 4;

    // bias folded into accumulator init (column-only => all 4 C regs equal)
    float bv[NR];
    #pragma unroll
    for (int ni = 0; ni < NR; ++ni)
        bv[ni] = bias[(size_t)e * bias_stride + n0 + wn + ni * 16 + rl];

    f32x4 acc[MR][NR];
    #pragma unroll
    for (int mi = 0; mi < MR; ++mi)
        #pragma unroll
        for (int ni = 0; ni < NR; ++ni) acc[mi][ni] = (f32x4)(bv[ni]);

    for (int kb = 0; kb < K; kb += 64) {
        #pragma unroll
        for (int i = 0; i < WMLD; ++i)
            gload16(asrc[i] + kb, &As[(i * 8 + w) * 512]);
        #pragma unroll
        for (int i = 0; i < WNLD; ++i)
            gload16(bsrc[i] + kb, &Bs[(i * 8 + w) * 512]);
        asm volatile("s_waitcnt vmcnt(0)" ::: "memory");
        __syncthreads();
        #pragma unroll
        for (int kk = 0; kk < 2; ++kk) {
            int kof = kk * 32 + kq * 8;
            bf16x8 b[NR];
            #pragma unroll
            for (int ni = 0; ni < NR; ++ni) {
                int r = wn + ni * 16 + rl;
                b[ni] = *(const bf16x8*)&Bs[r * 64 + (kof ^ ((r & 7) << 3))];
            }
            #pragma unroll
            for (int mh = 0; mh < MR / 4; ++mh) {
                bf16x8 a[4];
                #pragma unroll
                for (int mi = 0; mi < 4; ++mi) {
                    int r = wm + (mh * 4 + mi) * 16 + rl;
                    a[mi] = *(const bf16x8*)&As[r * 64 + (kof ^ ((r & 7) << 3))];
                }
                #pragma unroll
                for (int mi = 0; mi < 4; ++mi)
                    #pragma unroll
                    for (int ni = 0; ni < NR; ++ni)
                        acc[mh * 4 + mi][ni] = __builtin_amdgcn_mfma_f32_16x16x32_bf16(
                            a[mi], b[ni], acc[mh * 4 + mi][ni], 0, 0, 0);
            }
        }
        __syncthreads();
    }

    // epilogue: (gelu) + packed bf16 convert + store
    #pragma unroll
    for (int ni = 0; ni < NR; ++ni) {
        int c = n0 + wn + ni * 16 + rl;
        #pragma unroll
        for (int mi = 0; mi < MR; ++mi) {
            #pragma unroll
            for (int jp = 0; jp < 2; ++jp) {
                float g0 = acc[mi][ni][jp * 2 + 0];
                float g1 = acc[mi][ni][jp * 2 + 1];
                if (GELU) { g0 = gelu_fast(g0); g1 = gelu_fast(g1); }
                unsigned pk;
                asm("v_cvt_pk_bf16_f32 %0, %1, %2" : "=v"(pk) : "v"(g0), "v"(g1));
                int r = wm + mi * 16 + kq * 4 + jp * 2;
                unsigned short* p = out + (size_t)(rowbase + r) * ldo + c;
                p[0]   = (unsigned short)pk;
                p[ldo] = (unsigned short)(pk >> 16);
            }
        }
    }
}

// ---------------- pass3: gather 4 bf16 rows, /4, LayerNorm ----------------
__global__ __launch_bounds__(256) void pass3_kernel(
        const unsigned short* __restrict__ oslab, const int* __restrict__ selpk,
        const int* __restrict__ slotpk, const int* __restrict__ cnt,
        const float* __restrict__ gamma, const float* __restrict__ beta,
        float* __restrict__ out) {
    int t = blockIdx.x;
    int seg[4], pc[4];
    seg_of(cnt, seg, pc);
    int sp = selpk[t], sl = slotpk[t];
    int e0 = sp & 0xff, e1 = (sp >> 8) & 0xff;
    int s0 = sl & 0xffff, s1 = (sl >> 16) & 0xffff;
    const unsigned short* p0 = oslab + (size_t)t * D_MODEL;
    const unsigned short* p1 = oslab + (size_t)(NTOK + t) * D_MODEL;
    const unsigned short* p2 = oslab + (size_t)(seg[e0] + s0) * D_MODEL;
    const unsigned short* p3 = oslab + (size_t)(seg[e1] + s1) * D_MODEL;
    float c[4];
    float sum = 0.f, sq = 0.f;
    #pragma unroll
    for (int i = 0; i < 4; ++i) {
        int d = threadIdx.x + i * 256;
        float v = (b2f(p0[d]) + b2f(p1[d]) + b2f(p2[d]) + b2f(p3[d])) * 0.25f;
        c[i] = v; sum += v; sq += v * v;
    }
    #pragma unroll
    for (int off = 32; off; off >>= 1) {
        sum += __shfl_xor(sum, off);
        sq  += __shfl_xor(sq, off);
    }
    __shared__ float red[8];
    int lane = threadIdx.x & 63, wid = threadIdx.x >> 6;
    if (lane == 0) { red[wid] = sum; red[4 + wid] = sq; }
    __syncthreads();
    sum = red[0] + red[1] + red[2] + red[3];
    sq  = red[4] + red[5] + red[6] + red[7];
    float mean = sum * (1.0f / 1024.0f);
    float var = sq * (1.0f / 1024.0f) - mean * mean;
    float inv = rsqrtf(var + LN_EPS);
    #pragma unroll
    for (int i = 0; i < 4; ++i) {
        int d = threadIdx.x + i * 256;
        out[(size_t)t * D_MODEL + d] = (c[i] - mean) * inv * gamma[d] + beta[d];
    }
}

extern "C" void kernel_launch(void* const* d_in, const int* in_sizes, int n_in,
                              void* d_out, int out_size, void* d_ws, size_t ws_size,
                              hipStream_t stream) {
    const float* x   = (const float*)d_in[0];
    const float* rW  = (const float*)d_in[1];
    const float* W1  = (const float*)d_in[2];
    const float* b1  = (const float*)d_in[3];
    const float* W2  = (const float*)d_in[4];
    const float* b2  = (const float*)d_in[5];
    const float* gam = (const float*)d_in[6];
    const float* bet = (const float*)d_in[7];
    float* out = (float*)d_out;
    float* logits = out + (size_t)NTOK * D_MODEL;

    char* ws = (char*)d_ws;
    int* cnt    = (int*)ws;                     // 4 counters, 128B apart
    int* selpk  = (int*)(ws + 0x1000);
    int* slotpk = (int*)(ws + 0x6000);
    int* list   = (int*)(ws + 0xB000);          // 4*4096*4 = 64KB
    unsigned short* xb    = (unsigned short*)(ws + 0x20000);    // 8 MiB
    unsigned short* W1t   = (unsigned short*)(ws + 0x820000);   // 48 MiB
    unsigned short* W2t   = (unsigned short*)(ws + 0x3820000);  // 48 MiB
    unsigned short* oslab = (unsigned short*)(ws + 0x6820000);  // 17408*1024*2 = 34 MiB
    unsigned short* h     = (unsigned short*)(ws + 0x8A20000);  // 17408*4096*2 = 136 MiB
    // total ≈ 287.4 MB (proven available)

    hipMemsetAsync(cnt, 0, 512, stream);
    router_kernel<<<NTOK / 4, 256, 0, stream>>>(x, rW, logits, selpk, slotpk, cnt, list, xb);
    transpose_kernel<<<dim3(D_FF / 64, D_MODEL / 64, 6), 256, 0, stream>>>(W1, W1t, D_MODEL, D_FF);
    transpose_kernel<<<dim3(D_MODEL / 64, D_FF / 64, 6), 256, 0, stream>>>(W2, W2t, D_FF, D_MODEL);

    // pass1: h = gelu(x @ W1^T + b1)   BM=256, BN=256, waves 2x4 (128x64 each)
    // grid (16, 16, 6) => nwg 1536 (mult of 32); LDS 64KB -> 2 blocks/CU
    gemm_kernel<1, 256, 256, 2, 4, 16, 16><<<dim3(16, 16, 6), 512, 0, stream>>>(
        xb, W1t, b1, D_FF, D_FF, h, cnt, list, D_MODEL);
    // pass2: oslab = h @ W2^T + b2     BM=128, BN=256, waves 2x4 (64x64 each)
    // grid (4, 32, 6) => nwg 768 (mult of 32) — r12-identical config
    gemm_kernel<0, 128, 256, 2, 4, 4, 32><<<dim3(4, 32, 6), 512, 0, stream>>>(
        h, W2t, b2, D_MODEL, D_MODEL, oslab, cnt, list, D_FF);

    pass3_kernel<<<NTOK, 256, 0, stream>>>(oslab, selpk, slotpk, cnt, gam, bet, out);
}

// Round 15
// 485.839 us; speedup vs baseline: 1.1171x; 1.1171x over previous
//
#include <hip/hip_runtime.h>
#include <cstdint>
#include <cstddef>

#define D_MODEL 1024
#define D_FF 4096
#define NTOK 4096
#define LN_EPS 1e-5f

typedef __bf16 bf16x8 __attribute__((ext_vector_type(8)));
typedef float f32x4 __attribute__((ext_vector_type(4)));
typedef unsigned short u16x4 __attribute__((ext_vector_type(4)));
typedef unsigned short u16x8 __attribute__((ext_vector_type(8)));

static __device__ __forceinline__ unsigned short f2bf(float f) {
    union { float f; unsigned u; } v; v.f = f;
    unsigned r = v.u + 0x7fffu + ((v.u >> 16) & 1u);
    return (unsigned short)(r >> 16);
}

static __device__ __forceinline__ float b2f(unsigned short u) {
    union { unsigned u; float f; } v; v.u = (unsigned)u << 16;
    return v.f;
}

// tanh-form GELU as x*sigmoid(2u), log2e pre-folded (proven round 7)
static __device__ __forceinline__ float gelu_fast(float x) {
    float x2 = x * x;
    float a2 = x * __builtin_fmaf(-0.1029432f, x2, -2.3022084f);  // -2u*log2(e)
    float e = __builtin_amdgcn_exp2f(a2);
    return x * __builtin_amdgcn_rcpf(1.0f + e);
}

static __device__ __forceinline__ void gload16(const void* g, void* l) {
    __builtin_amdgcn_global_load_lds(
        (const __attribute__((address_space(1))) void*)g,
        (__attribute__((address_space(3))) void*)l, 16, 0, 0);
}

// padded (256-aligned) prefix offsets of the 4 variable experts in the row slab
static __device__ __forceinline__ void seg_of(const int* cnt, int seg[4], int pc[4]) {
    int o = 2 * NTOK;
    #pragma unroll
    for (int e = 0; e < 4; ++e) {
        int c = cnt[e * 32];
        pc[e] = (c + 255) & ~255;
        seg[e] = o;
        o += pc[e];
    }
}

// ---------------- W [E][K][N] f32 -> Wt [E][N][K] bf16 ----------------
__global__ __launch_bounds__(256) void transpose_kernel(const float* __restrict__ W,
                                                        unsigned short* __restrict__ Wt,
                                                        int K, int N) {
    __shared__ unsigned short t[64][65];
    int k0 = blockIdx.y * 64, n0 = blockIdx.x * 64;
    const float* We = W + (size_t)blockIdx.z * K * N;
    unsigned short* Wte = Wt + (size_t)blockIdx.z * K * N;
    #pragma unroll
    for (int i = 0; i < 4; ++i) {
        int idx = threadIdx.x + i * 256;
        int kr = idx >> 4, c4 = idx & 15;
        f32x4 v = *(const f32x4*)&We[(size_t)(k0 + kr) * N + n0 + c4 * 4];
        #pragma unroll
        for (int j = 0; j < 4; ++j) t[c4 * 4 + j][kr] = f2bf(v[j]);
    }
    __syncthreads();
    #pragma unroll
    for (int i = 0; i < 2; ++i) {
        int idx = threadIdx.x + i * 256;
        int nr = idx >> 3, ck = idx & 7;
        u16x8 w;
        #pragma unroll
        for (int j = 0; j < 8; ++j) w[j] = t[nr][ck * 8 + j];
        *(u16x8*)&Wte[(size_t)(n0 + nr) * K + k0 + ck * 8] = w;
    }
}

// ------- router (fused x->bf16 convert): logits + top-2 + compaction + xb -----
__global__ __launch_bounds__(256) void router_kernel(
        const float* __restrict__ x, const float* __restrict__ rW,
        float* __restrict__ logits, int* __restrict__ selpk,
        int* __restrict__ slotpk, int* __restrict__ cnt, int* __restrict__ list,
        unsigned short* __restrict__ xb) {
    __shared__ int se[8];
    __shared__ int sslot[8];
    int wid = threadIdx.x >> 6, lane = threadIdx.x & 63;
    int t = blockIdx.x * 4 + wid;
    const float* xr = x + (size_t)t * D_MODEL;
    unsigned short* xbr = xb + (size_t)t * D_MODEL;
    float a0 = 0.f, a1 = 0.f, a2 = 0.f, a3 = 0.f;
    #pragma unroll
    for (int i = 0; i < 4; ++i) {
        int d4 = lane + i * 64;                 // float4 index within row
        f32x4 xv = *(const f32x4*)&xr[d4 * 4];
        u16x4 bo;
        #pragma unroll
        for (int j = 0; j < 4; ++j) {
            float xj = xv[j];
            f32x4 wv = *(const f32x4*)&rW[(d4 * 4 + j) * 4];
            a0 = __builtin_fmaf(xj, wv[0], a0);
            a1 = __builtin_fmaf(xj, wv[1], a1);
            a2 = __builtin_fmaf(xj, wv[2], a2);
            a3 = __builtin_fmaf(xj, wv[3], a3);
            bo[j] = f2bf(xj);
        }
        *(u16x4*)&xbr[d4 * 4] = bo;
    }
    #pragma unroll
    for (int off = 32; off; off >>= 1) {
        a0 += __shfl_xor(a0, off); a1 += __shfl_xor(a1, off);
        a2 += __shfl_xor(a2, off); a3 += __shfl_xor(a3, off);
    }
    if (lane == 0) {
        float l[4] = {a0, a1, a2, a3};
        logits[t * 4 + 0] = a0; logits[t * 4 + 1] = a1;
        logits[t * 4 + 2] = a2; logits[t * 4 + 3] = a3;
        int e0 = 0; float b = l[0];
        #pragma unroll
        for (int e = 1; e < 4; ++e) if (l[e] > b) { b = l[e]; e0 = e; }
        int e1 = -1; float b2 = -1e30f;
        #pragma unroll
        for (int e = 0; e < 4; ++e) {
            if (e == e0) continue;
            if (l[e] > b2) { b2 = l[e]; e1 = e; }
        }
        se[wid * 2] = e0; se[wid * 2 + 1] = e1;
    }
    __syncthreads();
    if (threadIdx.x == 0) {
        int cnts[4] = {0, 0, 0, 0}, base[4];
        #pragma unroll
        for (int k = 0; k < 8; ++k) cnts[se[k]]++;
        #pragma unroll
        for (int e = 0; e < 4; ++e)
            if (cnts[e]) base[e] = atomicAdd(&cnt[e * 32], cnts[e]);
        int run[4] = {0, 0, 0, 0};
        #pragma unroll
        for (int k = 0; k < 8; ++k) {
            int e = se[k];
            int s = base[e] + run[e]++;
            sslot[k] = s;
            list[e * NTOK + s] = blockIdx.x * 4 + (k >> 1);
        }
    }
    __syncthreads();
    if (lane == 0) {
        selpk[t] = se[wid * 2] | (se[wid * 2 + 1] << 8);
        slotpk[t] = sslot[wid * 2] | (sslot[wid * 2 + 1] << 16);
    }
}

// ---------- 256x256 8-phase GEMM (faithful m201-style port, r15) --------------
// 8 waves (2M x 4N), per-wave C = 128x64 (acc[8][4] -> AGPRs, r4-proven).
// LDS [2 dbuf][A/B][256][64] = 128 KiB, rows 128B with the PROVEN involution
// swizzle (piece (l&7)^(row&7)); half-tiles split BY ROWS (not K) so staging
// keeps full-line fetches (fixes r5's two regressions).
// Schedule per K-tile pair (E=buf0 ph1-4, O=buf1 ph5-8), one half-tile (2
// gloads/thread) staged per phase at its region's death point:
//   ph1-2: A(O)->buf1 (dead since prev ph8) | ph3-4: B(E+2)->buf0 (dead ph1)
//   ph5-6: A(E+2)->buf0 (dead ph4)          | ph7-8: B(O+2)->buf1 (dead ph5)
// vmcnt(4) ONLY at ph4/ph8 ends (proves all but newest 2 phases' loads landed;
// never drains mid-loop). B-frags reg-cached per tile (ph1/ph5); A-subtile per
// phase; 16 MFMA/phase in a setprio(1) cluster (T5 pays on this structure).
template<int GELU, int GX, int GY>
__global__ __launch_bounds__(512) void gemm8p_kernel(
        const unsigned short* __restrict__ A, const unsigned short* __restrict__ B,
        const float* __restrict__ bias, int bias_stride, int ldo,
        unsigned short* __restrict__ out,
        const int* __restrict__ cnt, const int* __restrict__ list, int K) {
    __shared__ unsigned short lds[2][2][256 * 64];

    // balanced quad-XCD swizzle (nwg multiple of 32 for both passes)
    const int D = blockIdx.x + GX * (blockIdx.y + GY * blockIdx.z);
    const int tq = D >> 3;
    const int W = ((D & 7) << 2) + ((tq >> 2) << 5) + (tq & 3);
    const int bx = W % GX;
    const int rem = W / GX;
    const int by = rem % GY;
    const int e  = rem / GY;

    const int tid = threadIdx.x, l = tid & 63, w = tid >> 6;
    int ecnt = NTOK, rowbase;
    if (e < 2) {
        rowbase = e * NTOK + by * 256;
    } else {
        int seg[4], pc[4];
        seg_of(cnt, seg, pc);
        int ev = e - 2;
        ecnt = cnt[ev * 32];
        if (by * 256 >= pc[ev]) return;   // before any barrier
        rowbase = seg[ev] + by * 256;
    }
    const int n0 = bx * 256;
    const unsigned short* Be = B + (size_t)e * (D_FF * D_MODEL);

    // staging sources: hj = h*2+j covers row h*128 + j*64 + w*8 + (l>>3),
    // source piece (l&7)^(row&7) (involution, linear LDS dest)
    const unsigned short* asrc[4];
    const unsigned short* bsrc[4];
    #pragma unroll
    for (int hj = 0; hj < 4; ++hj) {
        int row = (hj >> 1) * 128 + (hj & 1) * 64 + w * 8 + (l >> 3);
        int piece = ((l & 7) ^ (row & 7)) << 3;
        size_t arow;
        if (GELU) {
            int s = by * 256 + row;
            if (e < 2) arow = (size_t)s;
            else       arow = (size_t)((s < ecnt) ? list[(e - 2) * NTOK + s] : 0);
        } else {
            arow = (size_t)(rowbase + row);
        }
        asrc[hj] = A + arow * K + piece;
        bsrc[hj] = Be + (size_t)(n0 + row) * K + piece;
    }

    const int wr = w >> 2, wc = w & 3;
    const int rl = l & 15, kq = l >> 4;

    // bias folded into accumulator init (column-only => all 4 C regs equal)
    float bv[4];
    #pragma unroll
    for (int ni = 0; ni < 4; ++ni)
        bv[ni] = bias[(size_t)e * bias_stride + n0 + wc * 64 + ni * 16 + rl];

    f32x4 acc[8][4];
    #pragma unroll
    for (int mi = 0; mi < 8; ++mi)
        #pragma unroll
        for (int ni = 0; ni < 4; ++ni) acc[mi][ni] = (f32x4)(bv[ni]);

    // clean the vmcnt ledger: bias/gather VMEM must be drained before staging
    asm volatile("" :: "v"(bv[0]), "v"(bv[1]), "v"(bv[2]), "v"(bv[3]));
    asm volatile("s_waitcnt vmcnt(0)" ::: "memory");

    // stage one half-tile (h) of matrix mat of tile t into buffer bf: 2 gloads
    #define STG1(bf, mat, h, j, t)                                              \
        gload16(((mat) ? bsrc[(h) * 2 + (j)] : asrc[(h) * 2 + (j)]) +           \
                    (size_t)(t) * 64,                                           \
                &lds[bf][mat][((h) * 128 + (j) * 64 + w * 8) * 64])
    #define STGU(bf, mat, h, t) { STG1(bf, mat, h, 0, t); STG1(bf, mat, h, 1, t); }

    // prologue: tile0 (A+B) -> buf0 (8 loads); tile1 B -> buf1 (4 loads)
    STGU(0, 0, 0, 0); STGU(0, 0, 1, 0);
    STGU(0, 1, 0, 0); STGU(0, 1, 1, 0);
    STGU(1, 1, 0, 1); STGU(1, 1, 1, 1);
    asm volatile("s_waitcnt vmcnt(4)" ::: "memory");   // tile0 fully landed
    __builtin_amdgcn_s_barrier();

    bf16x8 bfr[4][2];

    #define PHASE(bufR, q, LOADB, STAGE, ENDVM)                                 \
    {                                                                           \
        bf16x8 afr[2][2];                                                       \
        _Pragma("unroll")                                                       \
        for (int m2 = 0; m2 < 2; ++m2)                                          \
            _Pragma("unroll")                                                   \
            for (int kk = 0; kk < 2; ++kk) {                                    \
                int r = wr * 128 + ((q) * 2 + m2) * 16 + rl;                    \
                afr[m2][kk] = *(const bf16x8*)&lds[bufR][0]                     \
                    [r * 64 + ((kk * 32 + kq * 8) ^ ((r & 7) << 3))];           \
            }                                                                   \
        if (LOADB) {                                                            \
            _Pragma("unroll")                                                   \
            for (int ni = 0; ni < 4; ++ni)                                      \
                _Pragma("unroll")                                               \
                for (int kk = 0; kk < 2; ++kk) {                                \
                    int r = wc * 64 + ni * 16 + rl;                             \
                    bfr[ni][kk] = *(const bf16x8*)&lds[bufR][1]                 \
                        [r * 64 + ((kk * 32 + kq * 8) ^ ((r & 7) << 3))];       \
                }                                                               \
        }                                                                       \
        STAGE;                                                                  \
        __builtin_amdgcn_s_barrier();                                           \
        asm volatile("s_waitcnt lgkmcnt(0)" ::: "memory");                      \
        __builtin_amdgcn_sched_barrier(0);                                      \
        __builtin_amdgcn_s_setprio(1);                                          \
        _Pragma("unroll")                                                       \
        for (int m2 = 0; m2 < 2; ++m2)                                          \
            _Pragma("unroll")                                                   \
            for (int kk = 0; kk < 2; ++kk)                                      \
                _Pragma("unroll")                                               \
                for (int ni = 0; ni < 4; ++ni)                                  \
                    acc[(q) * 2 + m2][ni] =                                     \
                        __builtin_amdgcn_mfma_f32_16x16x32_bf16(                \
                            afr[m2][kk], bfr[ni][kk], acc[(q) * 2 + m2][ni],    \
                            0, 0, 0);                                           \
        __builtin_amdgcn_s_setprio(0);                                          \
        ENDVM;                                                                  \
        __builtin_amdgcn_s_barrier();                                           \
    }

    const int npairs = K / 128;
    #pragma unroll 1
    for (int p = 0; p < npairs; ++p) {
        const int t0 = 2 * p;
        const bool nl = (p + 1 < npairs);
        PHASE(0, 0, 1, { STGU(1, 0, 0, t0 + 1); }, {});
        PHASE(0, 1, 0, { STGU(1, 0, 1, t0 + 1); }, {});
        PHASE(0, 2, 0, { if (nl) STGU(0, 1, 0, t0 + 2); }, {});
        PHASE(0, 3, 0, { if (nl) STGU(0, 1, 1, t0 + 2); },
              { if (nl) { asm volatile("s_waitcnt vmcnt(4)" ::: "memory"); }
                else    { asm volatile("s_waitcnt vmcnt(0)" ::: "memory"); } });
        PHASE(1, 0, 1, { if (nl) STGU(0, 0, 0, t0 + 2); }, {});
        PHASE(1, 1, 0, { if (nl) STGU(0, 0, 1, t0 + 2); }, {});
        PHASE(1, 2, 0, { if (nl) STGU(1, 1, 0, t0 + 3); }, {});
        PHASE(1, 3, 0, { if (nl) STGU(1, 1, 1, t0 + 3); },
              { if (nl) { asm volatile("s_waitcnt vmcnt(4)" ::: "memory"); } });
    }
    #undef PHASE
    #undef STGU
    #undef STG1

    // epilogue: (gelu) + packed bf16 convert + store
    #pragma unroll
    for (int ni = 0; ni < 4; ++ni) {
        int c = n0 + wc * 64 + ni * 16 + rl;
        #pragma unroll
        for (int mi = 0; mi < 8; ++mi) {
            #pragma unroll
            for (int jp = 0; jp < 2; ++jp) {
                float g0 = acc[mi][ni][jp * 2 + 0];
                float g1 = acc[mi][ni][jp * 2 + 1];
                if (GELU) { g0 = gelu_fast(g0); g1 = gelu_fast(g1); }
                unsigned pk;
                asm("v_cvt_pk_bf16_f32 %0, %1, %2" : "=v"(pk) : "v"(g0), "v"(g1));
                int r = wr * 128 + mi * 16 + kq * 4 + jp * 2;
                unsigned short* ptr = out + (size_t)(rowbase + r) * ldo + c;
                ptr[0]   = (unsigned short)pk;
                ptr[ldo] = (unsigned short)(pk >> 16);
            }
        }
    }
}

// ---------------- pass3: gather 4 bf16 rows, /4, LayerNorm ----------------
__global__ __launch_bounds__(256) void pass3_kernel(
        const unsigned short* __restrict__ oslab, const int* __restrict__ selpk,
        const int* __restrict__ slotpk, const int* __restrict__ cnt,
        const float* __restrict__ gamma, const float* __restrict__ beta,
        float* __restrict__ out) {
    int t = blockIdx.x;
    int seg[4], pc[4];
    seg_of(cnt, seg, pc);
    int sp = selpk[t], sl = slotpk[t];
    int e0 = sp & 0xff, e1 = (sp >> 8) & 0xff;
    int s0 = sl & 0xffff, s1 = (sl >> 16) & 0xffff;
    const unsigned short* p0 = oslab + (size_t)t * D_MODEL;
    const unsigned short* p1 = oslab + (size_t)(NTOK + t) * D_MODEL;
    const unsigned short* p2 = oslab + (size_t)(seg[e0] + s0) * D_MODEL;
    const unsigned short* p3 = oslab + (size_t)(seg[e1] + s1) * D_MODEL;
    float c[4];
    float sum = 0.f, sq = 0.f;
    #pragma unroll
    for (int i = 0; i < 4; ++i) {
        int d = threadIdx.x + i * 256;
        float v = (b2f(p0[d]) + b2f(p1[d]) + b2f(p2[d]) + b2f(p3[d])) * 0.25f;
        c[i] = v; sum += v; sq += v * v;
    }
    #pragma unroll
    for (int off = 32; off; off >>= 1) {
        sum += __shfl_xor(sum, off);
        sq  += __shfl_xor(sq, off);
    }
    __shared__ float red[8];
    int lane = threadIdx.x & 63, wid = threadIdx.x >> 6;
    if (lane == 0) { red[wid] = sum; red[4 + wid] = sq; }
    __syncthreads();
    sum = red[0] + red[1] + red[2] + red[3];
    sq  = red[4] + red[5] + red[6] + red[7];
    float mean = sum * (1.0f / 1024.0f);
    float var = sq * (1.0f / 1024.0f) - mean * mean;
    float inv = rsqrtf(var + LN_EPS);
    #pragma unroll
    for (int i = 0; i < 4; ++i) {
        int d = threadIdx.x + i * 256;
        out[(size_t)t * D_MODEL + d] = (c[i] - mean) * inv * gamma[d] + beta[d];
    }
}

extern "C" void kernel_launch(void* const* d_in, const int* in_sizes, int n_in,
                              void* d_out, int out_size, void* d_ws, size_t ws_size,
                              hipStream_t stream) {
    const float* x   = (const float*)d_in[0];
    const float* rW  = (const float*)d_in[1];
    const float* W1  = (const float*)d_in[2];
    const float* b1  = (const float*)d_in[3];
    const float* W2  = (const float*)d_in[4];
    const float* b2  = (const float*)d_in[5];
    const float* gam = (const float*)d_in[6];
    const float* bet = (const float*)d_in[7];
    float* out = (float*)d_out;
    float* logits = out + (size_t)NTOK * D_MODEL;

    char* ws = (char*)d_ws;
    int* cnt    = (int*)ws;                     // 4 counters, 128B apart
    int* selpk  = (int*)(ws + 0x1000);
    int* slotpk = (int*)(ws + 0x6000);
    int* list   = (int*)(ws + 0xB000);          // 4*4096*4 = 64KB
    unsigned short* xb    = (unsigned short*)(ws + 0x20000);    // 8 MiB
    unsigned short* W1t   = (unsigned short*)(ws + 0x820000);   // 48 MiB
    unsigned short* W2t   = (unsigned short*)(ws + 0x3820000);  // 48 MiB
    unsigned short* oslab = (unsigned short*)(ws + 0x6820000);  // 17408*1024*2 = 34 MiB
    unsigned short* h     = (unsigned short*)(ws + 0x8A20000);  // 17408*4096*2 = 136 MiB
    // total ≈ 287.4 MB (proven available)

    hipMemsetAsync(cnt, 0, 512, stream);
    router_kernel<<<NTOK / 4, 256, 0, stream>>>(x, rW, logits, selpk, slotpk, cnt, list, xb);
    transpose_kernel<<<dim3(D_FF / 64, D_MODEL / 64, 6), 256, 0, stream>>>(W1, W1t, D_MODEL, D_FF);
    transpose_kernel<<<dim3(D_MODEL / 64, D_FF / 64, 6), 256, 0, stream>>>(W2, W2t, D_FF, D_MODEL);

    // pass1: h = gelu(x @ W1^T + b1)   256x256 tiles; grid (16,16,6) = 1536 wg
    gemm8p_kernel<1, 16, 16><<<dim3(16, 16, 6), 512, 0, stream>>>(
        xb, W1t, b1, D_FF, D_FF, h, cnt, list, D_MODEL);
    // pass2: oslab = h @ W2^T + b2     256x256 tiles; grid (4,16,6) = 384 wg
    gemm8p_kernel<0, 4, 16><<<dim3(4, 16, 6), 512, 0, stream>>>(
        h, W2t, b2, D_MODEL, D_MODEL, oslab, cnt, list, D_FF);

    pass3_kernel<<<NTOK, 256, 0, stream>>>(oslab, selpk, slotpk, cnt, gam, bet, out);
}

// Round 16
// 458.061 us; speedup vs baseline: 1.1849x; 1.0606x over previous
//
#include <hip/hip_runtime.h>
#include <cstdint>
#include <cstddef>

#define D_MODEL 1024
#define D_FF 4096
#define NTOK 4096
#define LN_EPS 1e-5f

typedef __bf16 bf16x8 __attribute__((ext_vector_type(8)));
typedef float f32x4 __attribute__((ext_vector_type(4)));
typedef unsigned short u16x4 __attribute__((ext_vector_type(4)));
typedef unsigned short u16x8 __attribute__((ext_vector_type(8)));

static __device__ __forceinline__ unsigned short f2bf(float f) {
    union { float f; unsigned u; } v; v.f = f;
    unsigned r = v.u + 0x7fffu + ((v.u >> 16) & 1u);
    return (unsigned short)(r >> 16);
}

static __device__ __forceinline__ float b2f(unsigned short u) {
    union { unsigned u; float f; } v; v.u = (unsigned)u << 16;
    return v.f;
}

// tanh-form GELU as x*sigmoid(2u), log2e pre-folded (proven round 7)
static __device__ __forceinline__ float gelu_fast(float x) {
    float x2 = x * x;
    float a2 = x * __builtin_fmaf(-0.1029432f, x2, -2.3022084f);  // -2u*log2(e)
    float e = __builtin_amdgcn_exp2f(a2);
    return x * __builtin_amdgcn_rcpf(1.0f + e);
}

static __device__ __forceinline__ void gload16(const void* g, void* l) {
    __builtin_amdgcn_global_load_lds(
        (const __attribute__((address_space(1))) void*)g,
        (__attribute__((address_space(3))) void*)l, 16, 0, 0);
}

// padded (256-aligned) prefix offsets of the 4 variable experts in the row slab
static __device__ __forceinline__ void seg_of(const int* cnt, int seg[4], int pc[4]) {
    int o = 2 * NTOK;
    #pragma unroll
    for (int e = 0; e < 4; ++e) {
        int c = cnt[e * 32];
        pc[e] = (c + 255) & ~255;
        seg[e] = o;
        o += pc[e];
    }
}

// ---------------- fused prep kernel: router + both W transposes --------------
// blockIdx.x partition: [0,1024) router (4 tokens/block);
// [1024,7168) W1 transpose (x=64,y=16,z=6); [7168,13312) W2 (x=16,y=64,z=6).
// All 256-thread, memory-bound; fusing drops 2 launch gaps and co-schedules.

static __device__ __forceinline__ void transpose_body(
        const float* __restrict__ W, unsigned short* __restrict__ Wt,
        int K, int N, int bx, int by, int bz, unsigned short (*t)[65]) {
    int k0 = by * 64, n0 = bx * 64;
    const float* We = W + (size_t)bz * K * N;
    unsigned short* Wte = Wt + (size_t)bz * K * N;
    #pragma unroll
    for (int i = 0; i < 4; ++i) {
        int idx = threadIdx.x + i * 256;
        int kr = idx >> 4, c4 = idx & 15;
        f32x4 v = *(const f32x4*)&We[(size_t)(k0 + kr) * N + n0 + c4 * 4];
        #pragma unroll
        for (int j = 0; j < 4; ++j) t[c4 * 4 + j][kr] = f2bf(v[j]);
    }
    __syncthreads();
    #pragma unroll
    for (int i = 0; i < 2; ++i) {
        int idx = threadIdx.x + i * 256;
        int nr = idx >> 3, ck = idx & 7;
        u16x8 w;
        #pragma unroll
        for (int j = 0; j < 8; ++j) w[j] = t[nr][ck * 8 + j];
        *(u16x8*)&Wte[(size_t)(n0 + nr) * K + k0 + ck * 8] = w;
    }
}

static __device__ __forceinline__ void router_body(
        int bid, const float* __restrict__ x, const float* __restrict__ rW,
        float* __restrict__ logits, int* __restrict__ selpk,
        int* __restrict__ slotpk, int* __restrict__ cnt, int* __restrict__ list,
        unsigned short* __restrict__ xb, int* se, int* sslot) {
    int wid = threadIdx.x >> 6, lane = threadIdx.x & 63;
    int t = bid * 4 + wid;
    const float* xr = x + (size_t)t * D_MODEL;
    unsigned short* xbr = xb + (size_t)t * D_MODEL;
    float a0 = 0.f, a1 = 0.f, a2 = 0.f, a3 = 0.f;
    #pragma unroll
    for (int i = 0; i < 4; ++i) {
        int d4 = lane + i * 64;                 // float4 index within row
        f32x4 xv = *(const f32x4*)&xr[d4 * 4];
        u16x4 bo;
        #pragma unroll
        for (int j = 0; j < 4; ++j) {
            float xj = xv[j];
            f32x4 wv = *(const f32x4*)&rW[(d4 * 4 + j) * 4];
            a0 = __builtin_fmaf(xj, wv[0], a0);
            a1 = __builtin_fmaf(xj, wv[1], a1);
            a2 = __builtin_fmaf(xj, wv[2], a2);
            a3 = __builtin_fmaf(xj, wv[3], a3);
            bo[j] = f2bf(xj);
        }
        *(u16x4*)&xbr[d4 * 4] = bo;
    }
    #pragma unroll
    for (int off = 32; off; off >>= 1) {
        a0 += __shfl_xor(a0, off); a1 += __shfl_xor(a1, off);
        a2 += __shfl_xor(a2, off); a3 += __shfl_xor(a3, off);
    }
    if (lane == 0) {
        float l[4] = {a0, a1, a2, a3};
        logits[t * 4 + 0] = a0; logits[t * 4 + 1] = a1;
        logits[t * 4 + 2] = a2; logits[t * 4 + 3] = a3;
        int e0 = 0; float b = l[0];
        #pragma unroll
        for (int e = 1; e < 4; ++e) if (l[e] > b) { b = l[e]; e0 = e; }
        int e1 = -1; float b2 = -1e30f;
        #pragma unroll
        for (int e = 0; e < 4; ++e) {
            if (e == e0) continue;
            if (l[e] > b2) { b2 = l[e]; e1 = e; }
        }
        se[wid * 2] = e0; se[wid * 2 + 1] = e1;
    }
    __syncthreads();
    if (threadIdx.x == 0) {
        int cnts[4] = {0, 0, 0, 0}, base[4];
        #pragma unroll
        for (int k = 0; k < 8; ++k) cnts[se[k]]++;
        #pragma unroll
        for (int e = 0; e < 4; ++e)
            if (cnts[e]) base[e] = atomicAdd(&cnt[e * 32], cnts[e]);
        int run[4] = {0, 0, 0, 0};
        #pragma unroll
        for (int k = 0; k < 8; ++k) {
            int e = se[k];
            int s = base[e] + run[e]++;
            sslot[k] = s;
            list[e * NTOK + s] = bid * 4 + (k >> 1);
        }
    }
    __syncthreads();
    if (lane == 0) {
        selpk[t] = se[wid * 2] | (se[wid * 2 + 1] << 8);
        slotpk[t] = sslot[wid * 2] | (sslot[wid * 2 + 1] << 16);
    }
}

__global__ __launch_bounds__(256) void prep_kernel(
        const float* __restrict__ x, const float* __restrict__ rW,
        float* __restrict__ logits, int* __restrict__ selpk,
        int* __restrict__ slotpk, int* __restrict__ cnt, int* __restrict__ list,
        unsigned short* __restrict__ xb,
        const float* __restrict__ W1, unsigned short* __restrict__ W1t,
        const float* __restrict__ W2, unsigned short* __restrict__ W2t) {
    __shared__ unsigned short tbuf[64][65];   // transpose tile; router reuses
    int bid = blockIdx.x;
    if (bid < 1024) {
        int* se = (int*)&tbuf[0][0];
        int* sslot = se + 8;
        router_body(bid, x, rW, logits, selpk, slotpk, cnt, list, xb, se, sslot);
    } else if (bid < 1024 + 6144) {
        int b = bid - 1024;                   // W1: K=1024, N=4096
        transpose_body(W1, W1t, D_MODEL, D_FF, b % 64, (b / 64) % 16, b / 1024, tbuf);
    } else {
        int b = bid - 7168;                   // W2: K=4096, N=1024
        transpose_body(W2, W2t, D_FF, D_MODEL, b % 16, (b / 16) % 64, b / 1024, tbuf);
    }
}

// ---------------- asymmetric-tile 2-barrier GEMM (round-12 proven best) -------
// BM = WM*64, BN = WN*64, WM*WN = 8 waves, per-wave C = 64x64, 48 KiB LDS.
// No min-occupancy launch_bounds (round-8 spill lesson). Simple 2-barrier loop
// (NINE pipeline/tile variants r4-r15 all lost to or tied this structure —
// multi-block TLP is what hides staging latency here, m114).
// Quad-XCD swizzle: work W = 4*(D&7) + 32*((D>>3)>>2) + ((D>>3)&3) — bijective
// for nwg%32==0; each XCD runs quads of 4 consecutive W sharing one A-panel.
template<int GELU, int WM, int WN, int GX, int GY>
__global__ __launch_bounds__(512) void gemm_kernel(
        const unsigned short* __restrict__ A, const unsigned short* __restrict__ B,
        const float* __restrict__ bias, int bias_stride, int ldo,
        unsigned short* __restrict__ out,
        const int* __restrict__ cnt, const int* __restrict__ list, int K) {
    constexpr int BM = WM * 64, BN = WN * 64;
    __shared__ unsigned short As[BM * 64];
    __shared__ unsigned short Bs[BN * 64];

    // balanced quad-XCD swizzle (nwg = GX*GY*6, multiple of 32 for both passes)
    const int D = blockIdx.x + GX * (blockIdx.y + GY * blockIdx.z);
    const int tq = D >> 3;
    const int W = ((D & 7) << 2) + ((tq >> 2) << 5) + (tq & 3);
    const int bx = W % GX;
    const int rem = W / GX;
    const int by = rem % GY;
    const int e  = rem / GY;

    const int tid = threadIdx.x, lane = tid & 63, w = tid >> 6;
    int ecnt = NTOK, rowbase;
    if (e < 2) {
        rowbase = e * NTOK + by * BM;
    } else {
        int seg[4], pc[4];
        seg_of(cnt, seg, pc);
        int ev = e - 2;
        ecnt = cnt[ev * 32];
        if (by * BM >= pc[ev]) return;   // before any barrier
        rowbase = seg[ev] + by * BM;
    }
    const int n0 = bx * BN;
    const unsigned short* Be = B + (size_t)e * (D_FF * D_MODEL);

    // per-thread staging sources (pre-swizzled source piece, linear LDS dest);
    // load i covers rows i*64 + w*8 + (lane>>3), piece (lane&7)^(row&7)
    const unsigned short* asrc[WM];
    const unsigned short* bsrc[WN];
    #pragma unroll
    for (int i = 0; i < WM; ++i) {
        int row = i * 64 + w * 8 + (lane >> 3);
        int kc = lane & 7;
        size_t arow;
        if (GELU) {
            int s = by * BM + row;
            if (e < 2) arow = (size_t)s;
            else       arow = (size_t)((s < ecnt) ? list[(e - 2) * NTOK + s] : 0);
        } else {
            arow = (size_t)(rowbase + row);
        }
        asrc[i] = A + arow * K + ((kc ^ (row & 7)) << 3);
    }
    #pragma unroll
    for (int i = 0; i < WN; ++i) {
        int row = i * 64 + w * 8 + (lane >> 3);
        int kc = lane & 7;
        bsrc[i] = Be + (size_t)(n0 + row) * K + ((kc ^ (row & 7)) << 3);
    }

    const int wm = (w / WN) * 64, wn = (w % WN) * 64;
    const int rl = lane & 15, kq = lane >> 4;

    // bias folded into accumulator init (column-only => all 4 C regs equal)
    float bv[4];
    #pragma unroll
    for (int ni = 0; ni < 4; ++ni)
        bv[ni] = bias[(size_t)e * bias_stride + n0 + wn + ni * 16 + rl];

    f32x4 acc[4][4];
    #pragma unroll
    for (int mi = 0; mi < 4; ++mi)
        #pragma unroll
        for (int ni = 0; ni < 4; ++ni) acc[mi][ni] = (f32x4)(bv[ni]);

    for (int kb = 0; kb < K; kb += 64) {
        #pragma unroll
        for (int i = 0; i < WM; ++i)
            gload16(asrc[i] + kb, &As[(i * 8 + w) * 512]);
        #pragma unroll
        for (int i = 0; i < WN; ++i)
            gload16(bsrc[i] + kb, &Bs[(i * 8 + w) * 512]);
        asm volatile("s_waitcnt vmcnt(0)" ::: "memory");
        __syncthreads();
        #pragma unroll
        for (int kk = 0; kk < 2; ++kk) {
            int kof = kk * 32 + kq * 8;
            bf16x8 a[4], b[4];
            #pragma unroll
            for (int mi = 0; mi < 4; ++mi) {
                int r = wm + mi * 16 + rl;
                a[mi] = *(const bf16x8*)&As[r * 64 + (kof ^ ((r & 7) << 3))];
            }
            #pragma unroll
            for (int ni = 0; ni < 4; ++ni) {
                int r = wn + ni * 16 + rl;
                b[ni] = *(const bf16x8*)&Bs[r * 64 + (kof ^ ((r & 7) << 3))];
            }
            #pragma unroll
            for (int mi = 0; mi < 4; ++mi)
                #pragma unroll
                for (int ni = 0; ni < 4; ++ni)
                    acc[mi][ni] = __builtin_amdgcn_mfma_f32_16x16x32_bf16(
                        a[mi], b[ni], acc[mi][ni], 0, 0, 0);
        }
        __syncthreads();
    }

    // epilogue: (gelu) + packed bf16 convert + store
    #pragma unroll
    for (int ni = 0; ni < 4; ++ni) {
        int c = n0 + wn + ni * 16 + rl;
        #pragma unroll
        for (int mi = 0; mi < 4; ++mi) {
            #pragma unroll
            for (int jp = 0; jp < 2; ++jp) {
                float g0 = acc[mi][ni][jp * 2 + 0];
                float g1 = acc[mi][ni][jp * 2 + 1];
                if (GELU) { g0 = gelu_fast(g0); g1 = gelu_fast(g1); }
                unsigned pk;
                asm("v_cvt_pk_bf16_f32 %0, %1, %2" : "=v"(pk) : "v"(g0), "v"(g1));
                int r = wm + mi * 16 + kq * 4 + jp * 2;
                unsigned short* p = out + (size_t)(rowbase + r) * ldo + c;
                p[0]   = (unsigned short)pk;
                p[ldo] = (unsigned short)(pk >> 16);
            }
        }
    }
}

// ---------------- pass3: gather 4 bf16 rows, /4, LayerNorm ----------------
__global__ __launch_bounds__(256) void pass3_kernel(
        const unsigned short* __restrict__ oslab, const int* __restrict__ selpk,
        const int* __restrict__ slotpk, const int* __restrict__ cnt,
        const float* __restrict__ gamma, const float* __restrict__ beta,
        float* __restrict__ out) {
    int t = blockIdx.x;
    int seg[4], pc[4];
    seg_of(cnt, seg, pc);
    int sp = selpk[t], sl = slotpk[t];
    int e0 = sp & 0xff, e1 = (sp >> 8) & 0xff;
    int s0 = sl & 0xffff, s1 = (sl >> 16) & 0xffff;
    const unsigned short* p0 = oslab + (size_t)t * D_MODEL;
    const unsigned short* p1 = oslab + (size_t)(NTOK + t) * D_MODEL;
    const unsigned short* p2 = oslab + (size_t)(seg[e0] + s0) * D_MODEL;
    const unsigned short* p3 = oslab + (size_t)(seg[e1] + s1) * D_MODEL;
    float c[4];
    float sum = 0.f, sq = 0.f;
    #pragma unroll
    for (int i = 0; i < 4; ++i) {
        int d = threadIdx.x + i * 256;
        float v = (b2f(p0[d]) + b2f(p1[d]) + b2f(p2[d]) + b2f(p3[d])) * 0.25f;
        c[i] = v; sum += v; sq += v * v;
    }
    #pragma unroll
    for (int off = 32; off; off >>= 1) {
        sum += __shfl_xor(sum, off);
        sq  += __shfl_xor(sq, off);
    }
    __shared__ float red[8];
    int lane = threadIdx.x & 63, wid = threadIdx.x >> 6;
    if (lane == 0) { red[wid] = sum; red[4 + wid] = sq; }
    __syncthreads();
    sum = red[0] + red[1] + red[2] + red[3];
    sq  = red[4] + red[5] + red[6] + red[7];
    float mean = sum * (1.0f / 1024.0f);
    float var = sq * (1.0f / 1024.0f) - mean * mean;
    float inv = rsqrtf(var + LN_EPS);
    #pragma unroll
    for (int i = 0; i < 4; ++i) {
        int d = threadIdx.x + i * 256;
        out[(size_t)t * D_MODEL + d] = (c[i] - mean) * inv * gamma[d] + beta[d];
    }
}

extern "C" void kernel_launch(void* const* d_in, const int* in_sizes, int n_in,
                              void* d_out, int out_size, void* d_ws, size_t ws_size,
                              hipStream_t stream) {
    const float* x   = (const float*)d_in[0];
    const float* rW  = (const float*)d_in[1];
    const float* W1  = (const float*)d_in[2];
    const float* b1  = (const float*)d_in[3];
    const float* W2  = (const float*)d_in[4];
    const float* b2  = (const float*)d_in[5];
    const float* gam = (const float*)d_in[6];
    const float* bet = (const float*)d_in[7];
    float* out = (float*)d_out;
    float* logits = out + (size_t)NTOK * D_MODEL;

    char* ws = (char*)d_ws;
    int* cnt    = (int*)ws;                     // 4 counters, 128B apart
    int* selpk  = (int*)(ws + 0x1000);
    int* slotpk = (int*)(ws + 0x6000);
    int* list   = (int*)(ws + 0xB000);          // 4*4096*4 = 64KB
    unsigned short* xb    = (unsigned short*)(ws + 0x20000);    // 8 MiB
    unsigned short* W1t   = (unsigned short*)(ws + 0x820000);   // 48 MiB
    unsigned short* W2t   = (unsigned short*)(ws + 0x3820000);  // 48 MiB
    unsigned short* oslab = (unsigned short*)(ws + 0x6820000);  // 17408*1024*2 = 34 MiB
    unsigned short* h     = (unsigned short*)(ws + 0x8A20000);  // 17408*4096*2 = 136 MiB
    // total ≈ 287.4 MB (proven available)

    hipMemsetAsync(cnt, 0, 512, stream);
    // fused prep: router (1024 blocks) + W1 transpose (6144) + W2 transpose (6144)
    prep_kernel<<<13312, 256, 0, stream>>>(x, rW, logits, selpk, slotpk, cnt, list,
                                           xb, W1, W1t, W2, W2t);

    // pass1: h = gelu(x @ W1^T + b1)   BM=256 (halve W1t re-reads), BN=128
    // grid (32, 16, 6) => nwg 3072 (mult of 32)
    gemm_kernel<1, 4, 2, 32, 16><<<dim3(32, 16, 6), 512, 0, stream>>>(
        xb, W1t, b1, D_FF, D_FF, h, cnt, list, D_MODEL);
    // pass2: oslab = h @ W2^T + b2     BM=128, BN=256 (halve h re-reads)
    // grid (4, 32, 6) => nwg 768 (mult of 32)
    gemm_kernel<0, 2, 4, 4, 32><<<dim3(4, 32, 6), 512, 0, stream>>>(
        h, W2t, b2, D_MODEL, D_MODEL, oslab, cnt, list, D_FF);

    pass3_kernel<<<NTOK, 256, 0, stream>>>(oslab, selpk, slotpk, cnt, gam, bet, out);
}